// Round 14
// baseline (1015.408 us; speedup 1.0000x reference)
//
#include <hip/hip_runtime.h>
#include <hip/hip_bf16.h>

#define NE 4
#define HD 768
#define F2 384
#define F1 192
#define NT 131072

typedef __attribute__((ext_vector_type(8))) short bf16x8;
typedef __attribute__((ext_vector_type(4))) float f32x4;
typedef __attribute__((ext_vector_type(4))) unsigned int u32x4;

// ws layout (bytes)
#define WS_BUCKET_OFF 256
#define WS_B1I_OFF  (WS_BUCKET_OFF + NE*NT*4)             // b1i: NE*2*192*768*2 = 2.36 MB
#define WS_DN2I_OFF (WS_B1I_OFF + NE*2*192*768*2)         // dn2i: NE*768*192*2 = 1.18 MB
#define WS_ACT_OFF  (WS_DN2I_OFF + NE*768*192*2)          // act: NT*192*2 = 50.3 MB
// b1i : [e][s2][c192][k768] k-contig; c<96 -> gate col s*96+c, else up col 192+s*96+(c-96)
// dn2i: [e][h768][f192] f-contig (= dn transposed)

__device__ __forceinline__ unsigned short f2bf(float x) {
    unsigned int u = __float_as_uint(x);
    return (unsigned short)((u + 0x7fffu + ((u >> 16) & 1u)) >> 16);
}
__device__ __forceinline__ unsigned int pk2(float a, float b) {
    unsigned int ua = __float_as_uint(a), ub = __float_as_uint(b);
    unsigned int lo = (ua + 0x7fffu + ((ua >> 16) & 1u)) >> 16;
    unsigned int hi = (ub + 0x7fffu + ((ub >> 16) & 1u)) & 0xffff0000u;
    return lo | hi;
}

__global__ void route_kernel(const int* __restrict__ ids, int* __restrict__ counts,
                             int* __restrict__ bucket) {
    __shared__ int lc[NE];
    __shared__ int lb[NE];
    int tid = threadIdx.x;
    if (tid < NE) lc[tid] = 0;
    __syncthreads();
    int t = blockIdx.x * blockDim.x + tid;
    int e = ids[t];
    int rank = atomicAdd(&lc[e], 1);
    __syncthreads();
    if (tid < NE) lb[tid] = atomicAdd(&counts[tid], lc[tid]);
    __syncthreads();
    bucket[e * NT + lb[e] + rank] = t;
}

// b1i[((e*2+s)*192+c)*768+k] = bf16(gu[(e*768+k)*384 + gc])
__global__ void b1i_kernel(const float* __restrict__ gu, unsigned short* __restrict__ b1i) {
    int idx = blockIdx.x * 256 + threadIdx.x;      // NE*2*192*768 = 1,179,648
    int k = idx % 768; int r = idx / 768;
    int c = r % 192; r /= 192;
    int s = r & 1; int e = r >> 1;
    int gc = (c < 96) ? (s * 96 + c) : (192 + s * 96 + (c - 96));
    b1i[idx] = f2bf(gu[((size_t)(e * HD + k)) * F2 + gc]);
}

// dn2i[(e*768+h)*192+f] = bf16(dn[(e*192+f)*768+h])
__global__ void dn2i_kernel(const float* __restrict__ dn, unsigned short* __restrict__ dn2i) {
    int idx = blockIdx.x * 256 + threadIdx.x;      // NE*768*192 = 589,824
    int f = idx % 192; int r = idx / 192;
    int h = r % 768; int e = r / 768;
    dn2i[idx] = f2bf(dn[((size_t)(e * F1 + f)) * HD + h]);
}

// ======= GEMM1 (barrier-free): wave = 16 tok x 192 vcols(gate96|up96), block = 4 waves x 4 rg =======
__global__ __launch_bounds__(256, 4)
void gemm1_kernel(const float* __restrict__ hidden, const int* __restrict__ counts,
                  const int* __restrict__ bucket, const unsigned short* __restrict__ b1i,
                  unsigned short* __restrict__ act)
{
    int bid = blockIdx.x;
    int s = bid & 1, tile = bid >> 1;
    int rem = tile, e, n_e = 0;
    for (e = 0; e < NE; ++e) {
        n_e = counts[e];
        int nt_ = (n_e + 63) >> 6;
        if (rem < nt_) break;
        rem -= nt_;
    }
    if (e >= NE) return;
    int t0 = rem << 6;

    int tid = threadIdx.x, lane = tid & 63, w = tid >> 6;
    int lg = lane >> 4, l16 = lane & 15;

    // A row token (per-lane; 4 lg-lanes share a row)
    int ra = t0 + w * 16 + l16; if (ra >= n_e) ra = n_e - 1;
    int tokA = bucket[e * NT + ra];
    const float* aptr = hidden + (size_t)tokA * HD + lg * 8;

    // B frag byte offsets: col = nt*16 + l16, k-octet lg
    const unsigned char* bimg = (const unsigned char*)(b1i + (size_t)(e * 2 + s) * 192 * 768);
    unsigned boff = (unsigned)((l16 * 768 + lg * 8) * 2);

    const f32x4 fzero = {0.f, 0.f, 0.f, 0.f};
    f32x4 acc[12];
    #pragma unroll
    for (int nt = 0; nt < 12; ++nt) acc[nt] = fzero;

    f32x4 ar[2][2];
    { const f32x4* p = (const f32x4*)aptr; ar[0][0] = p[0]; ar[0][1] = p[1]; }

    #pragma unroll 2
    for (int g = 0; g < 24; ++g) {
        // B(g): 12 frag loads (issued first -> retire first; in-order queue not blocked by A)
        bf16x8 Bf[12];
        #pragma unroll
        for (int nt = 0; nt < 12; ++nt)
            Bf[nt] = *(const bf16x8*)(bimg + boff + (unsigned)(nt * 16 * 768 * 2 + g * 64));
        // A(g+1) issued after B(g)
        if (g < 23) {
            const f32x4* p = (const f32x4*)(aptr + (g + 1) * 32);
            ar[(g + 1) & 1][0] = p[0]; ar[(g + 1) & 1][1] = p[1];
        }
        // convert A(g)
        f32x4 a0 = ar[g & 1][0], a1 = ar[g & 1][1];
        u32x4 cv = {pk2(a0.x, a0.y), pk2(a0.z, a0.w), pk2(a1.x, a1.y), pk2(a1.z, a1.w)};
        bf16x8 afr = __builtin_bit_cast(bf16x8, cv);

        #pragma unroll
        for (int nt = 0; nt < 12; ++nt)
            acc[nt] = __builtin_amdgcn_mfma_f32_16x16x32_bf16(afr, Bf[nt], acc[nt], 0, 0, 0);
    }

    // epilogue: silu(gate)*up -> act[tok][s*96 + nt*16 + l16]
    #pragma unroll
    for (int p = 0; p < 4; ++p) {
        int rs = t0 + w * 16 + lg * 4 + p;
        if (rs < n_e) {
            unsigned short* arow = act + (size_t)bucket[e * NT + rs] * F1 + s * 96 + l16;
            #pragma unroll
            for (int nt = 0; nt < 6; ++nt) {
                float g_ = acc[nt][p], u_ = acc[nt + 6][p];
                float a_ = g_ / (1.f + __expf(-g_)) * u_;
                arow[nt * 16] = f2bf(a_);
            }
        }
    }
}

// ======= GEMM2 (barrier-free): wave = 16 tok x 192 outcols, block = 4 waves x 4 rg =======
__global__ __launch_bounds__(256, 4)
void gemm2_kernel(const int* __restrict__ counts, const int* __restrict__ bucket,
                  const unsigned short* __restrict__ dn2i, const unsigned short* __restrict__ act,
                  float* __restrict__ out)
{
    int bid = blockIdx.x;
    int sl = bid & 3, tile = bid >> 2;
    int rem = tile, e, n_e = 0;
    for (e = 0; e < NE; ++e) {
        n_e = counts[e];
        int nt_ = (n_e + 63) >> 6;
        if (rem < nt_) break;
        rem -= nt_;
    }
    if (e >= NE) return;
    int t0 = rem << 6;

    int tid = threadIdx.x, lane = tid & 63, w = tid >> 6;
    int lg = lane >> 4, l16 = lane & 15;

    int ra = t0 + w * 16 + l16; if (ra >= n_e) ra = n_e - 1;
    int tokA = bucket[e * NT + ra];
    const unsigned short* aptr = act + (size_t)tokA * F1 + lg * 8;

    // B frag: col h = sl*192 + nt*16 + l16, k(f)-octet lg
    const unsigned char* bimg = (const unsigned char*)(dn2i + (size_t)e * HD * F1
                                                       + (size_t)(sl * 192) * F1);
    unsigned boff = (unsigned)((l16 * 192 + lg * 8) * 2);

    const f32x4 fzero = {0.f, 0.f, 0.f, 0.f};
    f32x4 acc[12];
    #pragma unroll
    for (int nt = 0; nt < 12; ++nt) acc[nt] = fzero;

    bf16x8 ar2[2];
    ar2[0] = *(const bf16x8*)aptr;

    #pragma unroll 2
    for (int kt = 0; kt < 6; ++kt) {
        bf16x8 Bf[12];
        #pragma unroll
        for (int nt = 0; nt < 12; ++nt)
            Bf[nt] = *(const bf16x8*)(bimg + boff + (unsigned)(nt * 16 * 192 * 2 + kt * 64));
        if (kt < 5) ar2[(kt + 1) & 1] = *(const bf16x8*)(aptr + (kt + 1) * 32);

        bf16x8 afr = ar2[kt & 1];
        #pragma unroll
        for (int nt = 0; nt < 12; ++nt)
            acc[nt] = __builtin_amdgcn_mfma_f32_16x16x32_bf16(afr, Bf[nt], acc[nt], 0, 0, 0);
    }

    #pragma unroll
    for (int p = 0; p < 4; ++p) {
        int rs = t0 + w * 16 + lg * 4 + p;
        if (rs < n_e) {
            float* orow = out + (size_t)bucket[e * NT + rs] * HD + sl * 192 + l16;
            #pragma unroll
            for (int nt = 0; nt < 12; ++nt)
                orow[nt * 16] = acc[nt][p];
        }
    }
}

extern "C" void kernel_launch(void* const* d_in, const int* in_sizes, int n_in,
                              void* d_out, int out_size, void* d_ws, size_t ws_size,
                              hipStream_t stream) {
    (void)in_sizes; (void)n_in; (void)out_size; (void)ws_size;
    const float* hidden = (const float*)d_in[0];
    const int*   ids    = (const int*)d_in[1];
    const float* gu     = (const float*)d_in[2];
    const float* dn     = (const float*)d_in[3];
    float* out = (float*)d_out;

    char* ws = (char*)d_ws;
    int* counts = (int*)ws;
    int* bucket = (int*)(ws + WS_BUCKET_OFF);
    unsigned short* b1i  = (unsigned short*)(ws + WS_B1I_OFF);
    unsigned short* dn2i = (unsigned short*)(ws + WS_DN2I_OFF);
    unsigned short* actw = (unsigned short*)(ws + WS_ACT_OFF);

    hipMemsetAsync(d_ws, 0, 64, stream);
    route_kernel<<<NT / 256, 256, 0, stream>>>(ids, counts, bucket);
    b1i_kernel<<<4608, 256, 0, stream>>>(gu, b1i);     // NE*2*192*768 elements
    dn2i_kernel<<<2304, 256, 0, stream>>>(dn, dn2i);   // NE*768*192 elements
    gemm1_kernel<<<4102, 256, 0, stream>>>(hidden, counts, bucket, b1i, actw);  // 2*(2048+3)
    gemm2_kernel<<<8204, 256, 0, stream>>>(counts, bucket, dn2i, actw, out);    // 4*(2048+3)
}

// Round 15
// 292.390 us; speedup vs baseline: 3.4728x; 3.4728x over previous
//
#include <hip/hip_runtime.h>
#include <hip/hip_bf16.h>

#define NE 4
#define HD 768
#define F2 384
#define F1 192
#define NT 131072
#define TT 128

typedef __attribute__((ext_vector_type(8))) short bf16x8;
typedef __attribute__((ext_vector_type(4))) float f32x4;
typedef __attribute__((ext_vector_type(4))) unsigned int u32x4;

// LDS (bytes):
//  GEMM1: A dbuf 0..32K (2x16K, [128][64] bf16 swz) ; B1 dbuf 32K..128K (2x48K = 2 sub-images each)
//  GEMM2: act 0..48K (overlays) ; B2 dbuf 48K..144K (2x48K)
//  tok 147456..
#define LA0 0u
#define LA1 16384u
#define LB0 32768u
#define LB1 81920u
#define LACT 0u
#define LC0 49152u
#define LC1 98304u
#define LTOK 147456u
#define SMEM_BYTES 147968

// workspace layout (bytes)
#define WS_BUCKET_OFF 256
#define WS_B1IMG_OFF (WS_BUCKET_OFF + NE*NT*4)            // B1 image: NE*24*24576 = 2.36 MB
#define WS_DNIMG_OFF (WS_B1IMG_OFF + NE*24*24576)         // B2 image: NE*12*24576 = 1.18 MB
// b1img: per (e,kstep32) a 24KB LDS byte-image; 16B unit L: colp=L>>3, slot=L&7,
//        v=slot^(colp&7), tilecol=colp*2+(v>>2), k=kstep*32+(v&3)*8  (k-contig in kstep)
// dnimg: per (e,half,kt32) a 24KB image, same unit mapping; col=h within half, k=f over 192

__device__ __forceinline__ unsigned short f2bf(float x) {
    unsigned int u = __float_as_uint(x);
    return (unsigned short)((u + 0x7fffu + ((u >> 16) & 1u)) >> 16);
}
__device__ __forceinline__ unsigned int pk2(float a, float b) {
    unsigned int ua = __float_as_uint(a), ub = __float_as_uint(b);
    unsigned int lo = (ua + 0x7fffu + ((ua >> 16) & 1u)) >> 16;
    unsigned int hi = (ub + 0x7fffu + ((ub >> 16) & 1u)) & 0xffff0000u;
    return lo | hi;
}
#define GLL(srcp, ldsoff) \
    __builtin_amdgcn_global_load_lds((const __attribute__((address_space(1))) void*)(srcp), \
        (__attribute__((address_space(3))) void*)(smem + (ldsoff)), 16, 0, 0)

__global__ void route_kernel(const int* __restrict__ ids, int* __restrict__ counts,
                             int* __restrict__ bucket) {
    __shared__ int lc[NE];
    __shared__ int lb[NE];
    int tid = threadIdx.x;
    if (tid < NE) lc[tid] = 0;
    __syncthreads();
    int t = blockIdx.x * blockDim.x + tid;
    int e = ids[t];
    int rank = atomicAdd(&lc[e], 1);
    __syncthreads();
    if (tid < NE) lb[tid] = atomicAdd(&counts[tid], lc[tid]);
    __syncthreads();
    bucket[e * NT + lb[e] + rank] = t;
}

__global__ void b1img_kernel(const float* __restrict__ gu, unsigned short* __restrict__ b1img) {
    int idx = blockIdx.x * 256 + threadIdx.x;      // NE*24*1536 = 147456
    int L = idx % 1536;
    int es = idx / 1536;
    int kstep = es % 24, e = es / 24;
    int colp = L >> 3, slot = L & 7;
    int v = slot ^ (colp & 7);
    int tc = colp * 2 + (v >> 2);
    int kb = kstep * 32 + (v & 3) * 8;
    const float* src = gu + ((size_t)(e * HD + kb)) * F2 + tc;
    unsigned short o[8];
    #pragma unroll
    for (int j = 0; j < 8; ++j) o[j] = f2bf(src[(size_t)j * F2]);
    *(bf16x8*)(b1img + ((size_t)idx) * 8) = *(const bf16x8*)o;
}

__global__ void dnimg_kernel(const float* __restrict__ dn, unsigned short* __restrict__ dnimg) {
    int idx = blockIdx.x * 256 + threadIdx.x;      // NE*2*6*1536 = 73728
    int L = idx % 1536;
    int r = idx / 1536;
    int kt = r % 6; r /= 6;
    int half = r & 1; int e = r >> 1;
    int colp = L >> 3, slot = L & 7;
    int v = slot ^ (colp & 7);
    int tc = colp * 2 + (v >> 2);
    int kb = kt * 32 + (v & 3) * 8;
    const float* src = dn + ((size_t)(e * F1 + kb)) * HD + half * 384 + tc;
    unsigned short o[8];
    #pragma unroll
    for (int j = 0; j < 8; ++j) o[j] = f2bf(src[(size_t)j * HD]);
    *(bf16x8*)(dnimg + ((size_t)idx) * 8) = *(const bf16x8*)o;
}

__global__ __launch_bounds__(512, 1)
void moe_kernel(const float* __restrict__ hidden, const int* __restrict__ counts,
                const int* __restrict__ bucket, const unsigned short* __restrict__ b1img,
                const unsigned short* __restrict__ dnimg, float* __restrict__ out)
{
    extern __shared__ __align__(16) unsigned char smem[];

    // exact block -> (expert, tile) mapping via prefix over counts
    int rem = blockIdx.x, e, n_e = 0;
    for (e = 0; e < NE; ++e) {
        n_e = counts[e];
        int ntiles = (n_e + TT - 1) >> 7;
        if (rem < ntiles) break;
        rem -= ntiles;
    }
    if (e >= NE) return;
    int t0 = rem << 7;

    int tid = threadIdx.x;
    int lane = tid & 63;
    int w = tid >> 6;
    int rw64 = (w >> 2) << 6;      // row half 0/64
    int cq = w & 3;                // col quarter
    int lg = lane >> 4;
    int l16 = lane & 15;

    int* tokp = (int*)(smem + LTOK);
    if (tid < TT) {
        int idx = t0 + tid; if (idx >= n_e) idx = n_e - 1;
        tokp[tid] = bucket[e * NT + idx];
    }
    __syncthreads();

    // ---- A staging: thread -> (row=tid>>2, kq=tid&3), 16 fp32 per BK=64 step ----
    int arow = tid >> 2, kq = tid & 3;
    const float* aptr = hidden + (size_t)tokp[arow] * HD + kq * 16;
    unsigned awb0 = (unsigned)(arow * 128 + (((2 * kq)     ^ (arow & 7)) << 4));
    unsigned awb1 = (unsigned)(arow * 128 + (((2 * kq + 1) ^ (arow & 7)) << 4));

    // ---- B1/B2 GLL sources (pre-swizzled images); per step: 2 sub-images x 3 chunks/wave ----
    const unsigned char* g1 = (const unsigned char*)b1img + (size_t)e * 589824
                              + (w * 3) * 1024 + lane * 16;
    const unsigned char* g2 = (const unsigned char*)dnimg + (size_t)e * 294912
                              + (w * 3) * 1024 + lane * 16;
    unsigned gld = (unsigned)(w * 3) * 1024u;

    // ---- fragment read addressing ----
    unsigned laneoff = (unsigned)(((l16 >> 1) << 7) +
                       (((lg + ((l16 & 1) << 2)) ^ (l16 >> 1)) << 4));
    unsigned arb[4], brb[6], b2rb[6];
    #pragma unroll
    for (int mt = 0; mt < 4; ++mt)
        arb[mt] = (unsigned)((rw64 + mt * 16 + l16) * 128);
    #pragma unroll
    for (int nt = 0; nt < 6; ++nt) {
        int tcb = (nt < 3) ? (cq * 48 + nt * 16) : (192 + cq * 48 + (nt - 3) * 16);
        brb[nt] = (unsigned)(tcb * 64) + laneoff;
        b2rb[nt] = (unsigned)((cq * 96 + nt * 16) * 64) + laneoff;
    }
    unsigned xk0 = (unsigned)((lg ^ (l16 & 7)) << 4);
    unsigned xk1 = (unsigned)(((4 + lg) ^ (l16 & 7)) << 4);

    f32x4 av[4];
    auto issueA = [&](int g) {
        const f32x4* p = (const f32x4*)(aptr + g * 64);
        av[0] = p[0]; av[1] = p[1]; av[2] = p[2]; av[3] = p[3];
    };
    auto writeA = [&](unsigned base) {
        u32x4 lo = {pk2(av[0].x,av[0].y), pk2(av[0].z,av[0].w), pk2(av[1].x,av[1].y), pk2(av[1].z,av[1].w)};
        u32x4 hi = {pk2(av[2].x,av[2].y), pk2(av[2].z,av[2].w), pk2(av[3].x,av[3].y), pk2(av[3].z,av[3].w)};
        *(u32x4*)(smem + base + awb0) = lo;
        *(u32x4*)(smem + base + awb1) = hi;
    };
    auto gllB1 = [&](int g, unsigned dstbase) {   // 48KB: sub-images 2g, 2g+1
        #pragma unroll
        for (int j = 0; j < 2; ++j)
            #pragma unroll
            for (int i = 0; i < 3; ++i)
                GLL(g1 + (size_t)(2 * g + j) * 24576 + i * 1024,
                    dstbase + (unsigned)j * 24576u + gld + i * 1024u);
    };
    auto gllB2 = [&](int q, unsigned dstbase) {   // q = half*3+s ; sub-images half*6+2s(+1)
        int h = q / 3, s = q % 3;
        #pragma unroll
        for (int j = 0; j < 2; ++j)
            #pragma unroll
            for (int i = 0; i < 3; ++i)
                GLL(g2 + (size_t)(h * 6 + 2 * s + j) * 24576 + i * 1024,
                    dstbase + (unsigned)j * 24576u + gld + i * 1024u);
    };

    const f32x4 fzero = {0.f, 0.f, 0.f, 0.f};
    f32x4 acc[4][6];
    #pragma unroll
    for (int mt = 0; mt < 4; ++mt)
        #pragma unroll
        for (int nt = 0; nt < 6; ++nt) acc[mt][nt] = fzero;

    // ================= GEMM1: C1[128][384], K=768, BK=64, 12 steps, 1-deep dbuf =================
    issueA(0);
    gllB1(0, LB0);
    writeA(LA0);
    asm volatile("s_waitcnt vmcnt(0) lgkmcnt(0)");
    __builtin_amdgcn_s_barrier();
    __builtin_amdgcn_sched_barrier(0);

    #pragma unroll 1
    for (int g = 0; g < 12; ++g) {
        unsigned Ab  = (g & 1) ? LA1 : LA0;
        unsigned Bb  = (g & 1) ? LB1 : LB0;
        unsigned Abn = (g & 1) ? LA0 : LA1;
        unsigned Bbn = (g & 1) ? LB0 : LB1;
        if (g < 11) { issueA(g + 1); gllB1(g + 1, Bbn); }

        #pragma unroll
        for (int kk = 0; kk < 2; ++kk) {
            unsigned xk = kk ? xk1 : xk0;
            unsigned bsub = Bb + (unsigned)kk * 24576u;
            bf16x8 Af[4], Bf[6];
            #pragma unroll
            for (int mt = 0; mt < 4; ++mt) Af[mt] = *(const bf16x8*)(smem + Ab + arb[mt] + xk);
            #pragma unroll
            for (int nt = 0; nt < 6; ++nt) Bf[nt] = *(const bf16x8*)(smem + bsub + brb[nt]);
            __builtin_amdgcn_s_setprio(1);
            #pragma unroll
            for (int nt = 0; nt < 6; ++nt)
                #pragma unroll
                for (int mt = 0; mt < 4; ++mt)
                    acc[mt][nt] = __builtin_amdgcn_mfma_f32_16x16x32_bf16(Af[mt], Bf[nt], acc[mt][nt], 0, 0, 0);
            __builtin_amdgcn_s_setprio(0);
        }

        if (g < 11) {
            writeA(Abn);
            asm volatile("s_waitcnt vmcnt(0) lgkmcnt(0)");
            __builtin_amdgcn_s_barrier();
            __builtin_amdgcn_sched_barrier(0);
        }
    }

    // all waves done reading LA1/LB1 before act overwrites LA*/LB0-head
    asm volatile("s_waitcnt lgkmcnt(0)");
    __builtin_amdgcn_s_barrier();
    __builtin_amdgcn_sched_barrier(0);

    // ================= act = silu(gate)*up -> LDS ; prefetch B2(q=0) under VALU =================
    gllB2(0, LC0);
    #pragma unroll
    for (int mt = 0; mt < 4; ++mt)
        #pragma unroll
        for (int nt = 0; nt < 3; ++nt)
            #pragma unroll
            for (int p = 0; p < 4; ++p) {
                float g = acc[mt][nt][p];
                float u = acc[mt][nt + 3][p];
                float s = g / (1.f + __expf(-g));
                int row = rw64 + mt * 16 + 4 * lg + p;
                int f = cq * 48 + nt * 16 + l16;
                int c = f >> 3;
                unsigned b = (unsigned)(LACT + row * 384 + (((c & 24) | ((c & 7) ^ (row & 7))) << 4) + (f & 7) * 2);
                *(unsigned short*)(smem + b) = f2bf(s * u);
            }
    asm volatile("s_waitcnt vmcnt(0) lgkmcnt(0)");   // act visible + B2(0) staged
    __builtin_amdgcn_s_barrier();
    __builtin_amdgcn_sched_barrier(0);

    // ================= GEMM2: out[128][768], K=192, BK=64, 6 steps (2 halves x 3) =================
    #pragma unroll
    for (int half = 0; half < 2; ++half) {
        f32x4 c2[4][6];
        #pragma unroll
        for (int mt = 0; mt < 4; ++mt)
            #pragma unroll
            for (int nt = 0; nt < 6; ++nt) c2[mt][nt] = fzero;

        #pragma unroll
        for (int s = 0; s < 3; ++s) {
            const int q = half * 3 + s;
            unsigned Cb = (q & 1) ? LC1 : LC0;
            if (q < 5) gllB2(q + 1, (q & 1) ? LC0 : LC1);

            #pragma unroll
            for (int kk = 0; kk < 2; ++kk) {
                int c = s * 8 + kk * 4 + lg;
                unsigned a2sl = (unsigned)(((c & 24) | ((c & 7) ^ (l16 & 7))) << 4);
                unsigned bsub = Cb + (unsigned)kk * 24576u;
                bf16x8 A2[4], B2f[6];
                #pragma unroll
                for (int mt = 0; mt < 4; ++mt)
                    A2[mt] = *(const bf16x8*)(smem + LACT + (rw64 + mt * 16 + l16) * 384 + a2sl);
                #pragma unroll
                for (int nt = 0; nt < 6; ++nt)
                    B2f[nt] = *(const bf16x8*)(smem + bsub + b2rb[nt]);
                __builtin_amdgcn_s_setprio(1);
                #pragma unroll
                for (int nt = 0; nt < 6; ++nt)
                    #pragma unroll
                    for (int mt = 0; mt < 4; ++mt)
                        c2[mt][nt] = __builtin_amdgcn_mfma_f32_16x16x32_bf16(A2[mt], B2f[nt], c2[mt][nt], 0, 0, 0);
                __builtin_amdgcn_s_setprio(0);
            }

            if (q < 5) {
                asm volatile("s_waitcnt vmcnt(0) lgkmcnt(0)");
                __builtin_amdgcn_s_barrier();
                __builtin_amdgcn_sched_barrier(0);
            }
        }

        #pragma unroll
        for (int mt = 0; mt < 4; ++mt)
            #pragma unroll
            for (int p = 0; p < 4; ++p) {
                int row = rw64 + mt * 16 + 4 * lg + p;
                if (t0 + row < n_e) {
                    float* orow = out + (size_t)tokp[row] * HD + half * 384 + cq * 96 + l16;
                    #pragma unroll
                    for (int nt = 0; nt < 6; ++nt)
                        orow[nt * 16] = c2[mt][nt][p];
                }
            }
    }
}

extern "C" void kernel_launch(void* const* d_in, const int* in_sizes, int n_in,
                              void* d_out, int out_size, void* d_ws, size_t ws_size,
                              hipStream_t stream) {
    (void)in_sizes; (void)n_in; (void)out_size; (void)ws_size;
    const float* hidden = (const float*)d_in[0];
    const int*   ids    = (const int*)d_in[1];
    const float* gu     = (const float*)d_in[2];
    const float* dn     = (const float*)d_in[3];
    float* out = (float*)d_out;

    char* ws = (char*)d_ws;
    int* counts = (int*)ws;
    int* bucket = (int*)(ws + WS_BUCKET_OFF);
    unsigned short* b1img = (unsigned short*)(ws + WS_B1IMG_OFF);
    unsigned short* dnimg = (unsigned short*)(ws + WS_DNIMG_OFF);

    hipMemsetAsync(d_ws, 0, 64, stream);
    route_kernel<<<NT / 256, 256, 0, stream>>>(ids, counts, bucket);
    b1img_kernel<<<576, 256, 0, stream>>>(gu, b1img);
    dnimg_kernel<<<288, 256, 0, stream>>>(dn, dnimg);
    moe_kernel<<<1028, 512, SMEM_BYTES, stream>>>(hidden, counts, bucket, b1img, dnimg, out);
}

// Round 16
// 284.039 us; speedup vs baseline: 3.5749x; 1.0294x over previous
//
#include <hip/hip_runtime.h>
#include <hip/hip_bf16.h>

#define NE 4
#define HD 768
#define F2 384
#define F1 192
#define NT 131072
#define TT 128

typedef __attribute__((ext_vector_type(8))) short bf16x8;
typedef __attribute__((ext_vector_type(4))) float f32x4;
typedef __attribute__((ext_vector_type(4))) unsigned int u32x4;

// LDS (bytes):
//  GEMM1: A dbuf 0..32K ; B1 dbuf 32K..128K (2x48K)
//  GEMM2: act 0..48K (overlays) ; B2 dbuf 48K..144K
#define LA0 0u
#define LA1 16384u
#define LB0 32768u
#define LB1 81920u
#define LACT 0u
#define LC0 49152u
#define LC1 98304u
#define LTOK 147456u
#define SMEM_BYTES 147968

// workspace layout (bytes)
#define WS_CNT_OFF 256
#define WS_BUCKET_OFF (256 + 8192)                        // cnt: 4 x 512 ints
#define WS_B1IMG_OFF (WS_BUCKET_OFF + NE*NT*4)
#define WS_DNIMG_OFF (WS_B1IMG_OFF + NE*24*24576)

__device__ __forceinline__ unsigned short f2bf(float x) {
    unsigned int u = __float_as_uint(x);
    return (unsigned short)((u + 0x7fffu + ((u >> 16) & 1u)) >> 16);
}
__device__ __forceinline__ unsigned int pk2(float a, float b) {
    unsigned int ua = __float_as_uint(a), ub = __float_as_uint(b);
    unsigned int lo = (ua + 0x7fffu + ((ua >> 16) & 1u)) >> 16;
    unsigned int hi = (ub + 0x7fffu + ((ub >> 16) & 1u)) & 0xffff0000u;
    return lo | hi;
}
#define GLL(srcp, ldsoff) \
    __builtin_amdgcn_global_load_lds((const __attribute__((address_space(1))) void*)(srcp), \
        (__attribute__((address_space(3))) void*)(smem + (ldsoff)), 16, 0, 0)

// ---- counting-sort routing: bucket[e] globally sorted by token id ----
__global__ void route1_kernel(const int* __restrict__ ids, int* __restrict__ cnt) {
    __shared__ int lc[NE];
    int tid = threadIdx.x;
    if (tid < NE) lc[tid] = 0;
    __syncthreads();
    int e = ids[blockIdx.x * 256 + tid];
    atomicAdd(&lc[e], 1);
    __syncthreads();
    if (tid < NE) cnt[tid * 512 + blockIdx.x] = lc[tid];
}

__global__ void route2_kernel(int* __restrict__ cnt, int* __restrict__ counts) {
    __shared__ int s[512];
    int tid = threadIdx.x;
    for (int e = 0; e < NE; ++e) {
        int orig = cnt[e * 512 + tid];
        s[tid] = orig; __syncthreads();
        #pragma unroll
        for (int off = 1; off < 512; off <<= 1) {
            int v = (tid >= off) ? s[tid - off] : 0; __syncthreads();
            s[tid] += v; __syncthreads();
        }
        cnt[e * 512 + tid] = s[tid] - orig;     // exclusive prefix
        if (tid == 511) counts[e] = s[511];
        __syncthreads();
    }
}

__global__ void route3_kernel(const int* __restrict__ ids, const int* __restrict__ cnt,
                              int* __restrict__ bucket) {
    __shared__ int lc[NE];
    int tid = threadIdx.x;
    if (tid < NE) lc[tid] = 0;
    __syncthreads();
    int t = blockIdx.x * 256 + tid;
    int e = ids[t];
    int r = atomicAdd(&lc[e], 1);
    bucket[e * NT + cnt[e * 512 + blockIdx.x] + r] = t;
}

__global__ void b1img_kernel(const float* __restrict__ gu, unsigned short* __restrict__ b1img) {
    int idx = blockIdx.x * 256 + threadIdx.x;      // NE*24*1536 = 147456
    int L = idx % 1536;
    int es = idx / 1536;
    int kstep = es % 24, e = es / 24;
    int colp = L >> 3, slot = L & 7;
    int v = slot ^ (colp & 7);
    int tc = colp * 2 + (v >> 2);
    int kb = kstep * 32 + (v & 3) * 8;
    const float* src = gu + ((size_t)(e * HD + kb)) * F2 + tc;
    unsigned short o[8];
    #pragma unroll
    for (int j = 0; j < 8; ++j) o[j] = f2bf(src[(size_t)j * F2]);
    *(bf16x8*)(b1img + ((size_t)idx) * 8) = *(const bf16x8*)o;
}

__global__ void dnimg_kernel(const float* __restrict__ dn, unsigned short* __restrict__ dnimg) {
    int idx = blockIdx.x * 256 + threadIdx.x;      // NE*2*6*1536 = 73728
    int L = idx % 1536;
    int r = idx / 1536;
    int kt = r % 6; r /= 6;
    int half = r & 1; int e = r >> 1;
    int colp = L >> 3, slot = L & 7;
    int v = slot ^ (colp & 7);
    int tc = colp * 2 + (v >> 2);
    int kb = kt * 32 + (v & 3) * 8;
    const float* src = dn + ((size_t)(e * F1 + kb)) * HD + half * 384 + tc;
    unsigned short o[8];
    #pragma unroll
    for (int j = 0; j < 8; ++j) o[j] = f2bf(src[(size_t)j * HD]);
    *(bf16x8*)(dnimg + ((size_t)idx) * 8) = *(const bf16x8*)o;
}

__global__ __launch_bounds__(512, 1)
void moe_kernel(const float* __restrict__ hidden, const int* __restrict__ counts,
                const int* __restrict__ bucket, const unsigned short* __restrict__ b1img,
                const unsigned short* __restrict__ dnimg, float* __restrict__ out)
{
    extern __shared__ __align__(16) unsigned char smem[];

    // window-major mapping: 4 complementary expert-blocks of one token window co-dispatch
    int e = blockIdx.x & 3;
    int tile = blockIdx.x >> 2;
    int n_e = counts[e];
    int t0 = tile << 7;
    if (t0 >= n_e) return;

    int tid = threadIdx.x;
    int lane = tid & 63;
    int w = tid >> 6;
    int rw64 = (w >> 2) << 6;      // row half 0/64
    int cq = w & 3;                // col quarter
    int lg = lane >> 4;
    int l16 = lane & 15;

    int* tokp = (int*)(smem + LTOK);
    if (tid < TT) {
        int idx = t0 + tid; if (idx >= n_e) idx = n_e - 1;
        tokp[tid] = bucket[e * NT + idx];
    }
    __syncthreads();

    // ---- A staging: thread -> (row=tid>>2, kq=tid&3), 16 fp32 per BK=64 step ----
    int arow = tid >> 2, kq = tid & 3;
    const float* aptr = hidden + (size_t)tokp[arow] * HD + kq * 16;
    unsigned awb0 = (unsigned)(arow * 128 + (((2 * kq)     ^ (arow & 7)) << 4));
    unsigned awb1 = (unsigned)(arow * 128 + (((2 * kq + 1) ^ (arow & 7)) << 4));

    // ---- B1/B2 GLL sources (pre-swizzled images); per step: 2 sub-images x 3 chunks/wave ----
    const unsigned char* g1 = (const unsigned char*)b1img + (size_t)e * 589824
                              + (w * 3) * 1024 + lane * 16;
    const unsigned char* g2 = (const unsigned char*)dnimg + (size_t)e * 294912
                              + (w * 3) * 1024 + lane * 16;
    unsigned gld = (unsigned)(w * 3) * 1024u;

    // ---- fragment read addressing ----
    unsigned laneoff = (unsigned)(((l16 >> 1) << 7) +
                       (((lg + ((l16 & 1) << 2)) ^ (l16 >> 1)) << 4));
    unsigned arb[4], brb[6], b2rb[6];
    #pragma unroll
    for (int mt = 0; mt < 4; ++mt)
        arb[mt] = (unsigned)((rw64 + mt * 16 + l16) * 128);
    #pragma unroll
    for (int nt = 0; nt < 6; ++nt) {
        int tcb = (nt < 3) ? (cq * 48 + nt * 16) : (192 + cq * 48 + (nt - 3) * 16);
        brb[nt] = (unsigned)(tcb * 64) + laneoff;
        b2rb[nt] = (unsigned)((cq * 96 + nt * 16) * 64) + laneoff;
    }
    unsigned xk0 = (unsigned)((lg ^ (l16 & 7)) << 4);
    unsigned xk1 = (unsigned)(((4 + lg) ^ (l16 & 7)) << 4);

    f32x4 av[4];
    auto issueA = [&](int g) {
        const f32x4* p = (const f32x4*)(aptr + g * 64);
        av[0] = p[0]; av[1] = p[1]; av[2] = p[2]; av[3] = p[3];
    };
    auto writeA = [&](unsigned base) {
        u32x4 lo = {pk2(av[0].x,av[0].y), pk2(av[0].z,av[0].w), pk2(av[1].x,av[1].y), pk2(av[1].z,av[1].w)};
        u32x4 hi = {pk2(av[2].x,av[2].y), pk2(av[2].z,av[2].w), pk2(av[3].x,av[3].y), pk2(av[3].z,av[3].w)};
        *(u32x4*)(smem + base + awb0) = lo;
        *(u32x4*)(smem + base + awb1) = hi;
    };
    auto gllB1 = [&](int g, unsigned dstbase) {
        #pragma unroll
        for (int j = 0; j < 2; ++j)
            #pragma unroll
            for (int i = 0; i < 3; ++i)
                GLL(g1 + (size_t)(2 * g + j) * 24576 + i * 1024,
                    dstbase + (unsigned)j * 24576u + gld + i * 1024u);
    };
    auto gllB2 = [&](int q, unsigned dstbase) {
        int h = q / 3, s = q % 3;
        #pragma unroll
        for (int j = 0; j < 2; ++j)
            #pragma unroll
            for (int i = 0; i < 3; ++i)
                GLL(g2 + (size_t)(h * 6 + 2 * s + j) * 24576 + i * 1024,
                    dstbase + (unsigned)j * 24576u + gld + i * 1024u);
    };

    const f32x4 fzero = {0.f, 0.f, 0.f, 0.f};
    f32x4 acc[4][6];
    #pragma unroll
    for (int mt = 0; mt < 4; ++mt)
        #pragma unroll
        for (int nt = 0; nt < 6; ++nt) acc[mt][nt] = fzero;

    // ================= GEMM1: C1[128][384], K=768, BK=64, 12 steps =================
    issueA(0);
    gllB1(0, LB0);
    writeA(LA0);
    asm volatile("s_waitcnt vmcnt(0) lgkmcnt(0)");
    __builtin_amdgcn_s_barrier();
    __builtin_amdgcn_sched_barrier(0);

    #pragma unroll 1
    for (int g = 0; g < 12; ++g) {
        unsigned Ab  = (g & 1) ? LA1 : LA0;
        unsigned Bb  = (g & 1) ? LB1 : LB0;
        unsigned Abn = (g & 1) ? LA0 : LA1;
        unsigned Bbn = (g & 1) ? LB0 : LB1;
        if (g < 11) { issueA(g + 1); gllB1(g + 1, Bbn); }

        #pragma unroll
        for (int kk = 0; kk < 2; ++kk) {
            unsigned xk = kk ? xk1 : xk0;
            unsigned bsub = Bb + (unsigned)kk * 24576u;
            bf16x8 Af[4], Bf[6];
            #pragma unroll
            for (int mt = 0; mt < 4; ++mt) Af[mt] = *(const bf16x8*)(smem + Ab + arb[mt] + xk);
            #pragma unroll
            for (int nt = 0; nt < 6; ++nt) Bf[nt] = *(const bf16x8*)(smem + bsub + brb[nt]);
            __builtin_amdgcn_s_setprio(1);
            #pragma unroll
            for (int nt = 0; nt < 6; ++nt)
                #pragma unroll
                for (int mt = 0; mt < 4; ++mt)
                    acc[mt][nt] = __builtin_amdgcn_mfma_f32_16x16x32_bf16(Af[mt], Bf[nt], acc[mt][nt], 0, 0, 0);
            __builtin_amdgcn_s_setprio(0);
        }

        if (g < 11) {
            writeA(Abn);
            asm volatile("s_waitcnt vmcnt(0) lgkmcnt(0)");
            __builtin_amdgcn_s_barrier();
            __builtin_amdgcn_sched_barrier(0);
        }
    }

    asm volatile("s_waitcnt lgkmcnt(0)");
    __builtin_amdgcn_s_barrier();
    __builtin_amdgcn_sched_barrier(0);

    // ================= act = silu(gate)*up -> LDS ; prefetch B2(0) =================
    gllB2(0, LC0);
    #pragma unroll
    for (int mt = 0; mt < 4; ++mt)
        #pragma unroll
        for (int nt = 0; nt < 3; ++nt)
            #pragma unroll
            for (int p = 0; p < 4; ++p) {
                float g = acc[mt][nt][p];
                float u = acc[mt][nt + 3][p];
                float s = g / (1.f + __expf(-g));
                int row = rw64 + mt * 16 + 4 * lg + p;
                int f = cq * 48 + nt * 16 + l16;
                int c = f >> 3;
                unsigned b = (unsigned)(LACT + row * 384 + (((c & 24) | ((c & 7) ^ (row & 7))) << 4) + (f & 7) * 2);
                *(unsigned short*)(smem + b) = f2bf(s * u);
            }
    asm volatile("s_waitcnt vmcnt(0) lgkmcnt(0)");
    __builtin_amdgcn_s_barrier();
    __builtin_amdgcn_sched_barrier(0);

    // ================= GEMM2: out[128][768], K=192, BK=64, 6 steps =================
    #pragma unroll
    for (int half = 0; half < 2; ++half) {
        f32x4 c2[4][6];
        #pragma unroll
        for (int mt = 0; mt < 4; ++mt)
            #pragma unroll
            for (int nt = 0; nt < 6; ++nt) c2[mt][nt] = fzero;

        #pragma unroll
        for (int s = 0; s < 3; ++s) {
            const int q = half * 3 + s;
            unsigned Cb = (q & 1) ? LC1 : LC0;
            if (q < 5) gllB2(q + 1, (q & 1) ? LC0 : LC1);

            #pragma unroll
            for (int kk = 0; kk < 2; ++kk) {
                int c = s * 8 + kk * 4 + lg;
                unsigned a2sl = (unsigned)(((c & 24) | ((c & 7) ^ (l16 & 7))) << 4);
                unsigned bsub = Cb + (unsigned)kk * 24576u;
                bf16x8 A2[4], B2f[6];
                #pragma unroll
                for (int mt = 0; mt < 4; ++mt)
                    A2[mt] = *(const bf16x8*)(smem + LACT + (rw64 + mt * 16 + l16) * 384 + a2sl);
                #pragma unroll
                for (int nt = 0; nt < 6; ++nt)
                    B2f[nt] = *(const bf16x8*)(smem + bsub + b2rb[nt]);
                __builtin_amdgcn_s_setprio(1);
                #pragma unroll
                for (int nt = 0; nt < 6; ++nt)
                    #pragma unroll
                    for (int mt = 0; mt < 4; ++mt)
                        c2[mt][nt] = __builtin_amdgcn_mfma_f32_16x16x32_bf16(A2[mt], B2f[nt], c2[mt][nt], 0, 0, 0);
                __builtin_amdgcn_s_setprio(0);
            }

            if (q < 5) {
                asm volatile("s_waitcnt vmcnt(0) lgkmcnt(0)");
                __builtin_amdgcn_s_barrier();
                __builtin_amdgcn_sched_barrier(0);
            }
        }

        #pragma unroll
        for (int mt = 0; mt < 4; ++mt)
            #pragma unroll
            for (int p = 0; p < 4; ++p) {
                int row = rw64 + mt * 16 + 4 * lg + p;
                if (t0 + row < n_e) {
                    float* orow = out + (size_t)tokp[row] * HD + half * 384 + cq * 96 + l16;
                    #pragma unroll
                    for (int nt = 0; nt < 6; ++nt)
                        orow[nt * 16] = c2[mt][nt][p];
                }
            }
    }
}

extern "C" void kernel_launch(void* const* d_in, const int* in_sizes, int n_in,
                              void* d_out, int out_size, void* d_ws, size_t ws_size,
                              hipStream_t stream) {
    (void)in_sizes; (void)n_in; (void)out_size; (void)ws_size;
    const float* hidden = (const float*)d_in[0];
    const int*   ids    = (const int*)d_in[1];
    const float* gu     = (const float*)d_in[2];
    const float* dn     = (const float*)d_in[3];
    float* out = (float*)d_out;

    char* ws = (char*)d_ws;
    int* counts = (int*)ws;
    int* cnt    = (int*)(ws + WS_CNT_OFF);
    int* bucket = (int*)(ws + WS_BUCKET_OFF);
    unsigned short* b1img = (unsigned short*)(ws + WS_B1IMG_OFF);
    unsigned short* dnimg = (unsigned short*)(ws + WS_DNIMG_OFF);

    route1_kernel<<<NT / 256, 256, 0, stream>>>(ids, cnt);
    route2_kernel<<<1, 512, 0, stream>>>(cnt, counts);
    route3_kernel<<<NT / 256, 256, 0, stream>>>(ids, cnt, bucket);
    b1img_kernel<<<576, 256, 0, stream>>>(gu, b1img);
    dnimg_kernel<<<288, 256, 0, stream>>>(dn, dnimg);
    moe_kernel<<<4 * 264, 512, SMEM_BYTES, stream>>>(hidden, counts, bucket, b1img, dnimg, out);
}